// Round 10
// baseline (178.978 us; speedup 1.0000x reference)
//
#include <hip/hip_runtime.h>
#include <math.h>

#define HEADS 8
#define DIM   64
#define DK    24
#define DHK   3
#define BB    4
#define HH    128
#define WW    128
#define NN    (HH*WW)
#define QSCALE 0.125f

// ---------------------------------------------------------------------------
// K1 v5: token-partial reduce. grid 1024 (4b x 256 chunks of 64 tokens) x
// 256 thr. Same proven inner body as R4, but 4x the blocks (TLP) and 1/4 the
// LDS (4-wave merge, 24.6KB -> ~6 blocks/CU vs R4's 98.5KB -> 1/CU).
// Plain stores -> Sp_part[1024][1536]. No atomics, no zeroing.
// ---------------------------------------------------------------------------
__global__ __launch_bounds__(256) void s_reduce(
    const float* __restrict__ imap,   // [B*N,24]
    const float* __restrict__ x,      // [B*N,64]
    float* __restrict__ Sp_part)      // [1024,1536]
{
    __shared__ float part[4 * 1540];    // 24.6 KB, stride 1540 (pad: %32==4)
    const int tid = threadIdx.x;
    const int blk = blockIdx.x;
    const int b = blk >> 8, chunk = blk & 255;
    const int w = tid >> 6, lane = tid & 63;
    const int cq = lane & 15;         // c = cq*4
    const int ig = lane >> 4;         // i = ig*6 .. +5

    const long tok0 = (long)b * NN + chunk * 64 + w * 16;
    const float* xp = x    + tok0 * 64 + cq * 4;
    const float* mp = imap + tok0 * 24 + ig * 6;

    float acc[6][4];
    #pragma unroll
    for (int r = 0; r < 6; ++r)
        #pragma unroll
        for (int q = 0; q < 4; ++q) acc[r][q] = 0.f;

    #pragma unroll 4
    for (int t = 0; t < 16; ++t) {
        float4 xv = *(const float4*)(xp + t * 64);
        float2 m0 = *(const float2*)(mp + t * 24);
        float2 m1 = *(const float2*)(mp + t * 24 + 2);
        float2 m2 = *(const float2*)(mp + t * 24 + 4);
        float mm[6] = {m0.x, m0.y, m1.x, m1.y, m2.x, m2.y};
        #pragma unroll
        for (int r = 0; r < 6; ++r) {
            acc[r][0] += mm[r] * xv.x;
            acc[r][1] += mm[r] * xv.y;
            acc[r][2] += mm[r] * xv.z;
            acc[r][3] += mm[r] * xv.w;
        }
    }

    float* pp = part + w * 1540;
    #pragma unroll
    for (int r = 0; r < 6; ++r) {
        float4 v = {acc[r][0], acc[r][1], acc[r][2], acc[r][3]};
        *(float4*)(pp + (ig * 6 + r) * 64 + cq * 4) = v;
    }
    __syncthreads();

    for (int e = tid; e < 1536; e += 256) {
        Sp_part[(long)blk * 1536 + e] =
            part[e] + part[1540 + e] + part[3080 + e] + part[4620 + e];
    }
}

// ---------------------------------------------------------------------------
// K2 v5: one block per BATCH (grid 4 x 1024). Eliminates the 8x redundant
// slab re-read (R4: 8 head-blocks each read the full batch slab set) and all
// Pt atomics (single owner -> plain stores; no pre-zeroing dispatch work).
//  - slab reduce: thread (p=tid&255, q=tid>>8): elements p+256k (k<6),
//    slabs q*64..+63 -> part[4][1536] -> LDS merge -> Sp_l. 384 loads/thread,
//    balanced, unroll for MLP.
//  - S, att, M, Pt phases: 1536 outputs over 1024 threads, R4-proven math.
//  - softmax: 24 rows; wave w handles row w (w<16) and w+16 (w<8).
// ---------------------------------------------------------------------------
__global__ __launch_bounds__(1024) void attn_fused(
    const float* __restrict__ Sp_part, // [1024,1536]
    const float* __restrict__ Wk,      // [24,24]
    const float* __restrict__ Wq,      // [64,512]
    const float* __restrict__ Wv,      // [64,512]
    const float* __restrict__ rescale, // [8]
    const float* __restrict__ Wp,      // [24,24]
    float* __restrict__ Pt)            // [4,1536] plain-stored here
{
    __shared__ float part[4 * 1536];   // 24.6 KB
    __shared__ float Sp_l[1536];
    __shared__ float S_l[1536];        // S rows; later reused for M
    __shared__ float att[1536];

    const int tid = threadIdx.x, b = blockIdx.x;
    const int w = tid >> 6, lane = tid & 63;

    // ---- 2-level slab reduce: 256 slabs of batch b ----
    {
        const int p = tid & 255, q = tid >> 8;
        const float* base = Sp_part + ((long)(b * 256 + q * 64)) * 1536;
        #pragma unroll
        for (int k = 0; k < 6; ++k) {
            const int e = k * 256 + p;
            const float* pp = base + e;
            float s = 0.f;
            #pragma unroll 16
            for (int sb = 0; sb < 64; ++sb) s += pp[(long)sb * 1536];
            part[q * 1536 + e] = s;
        }
    }
    __syncthreads();
    for (int e = tid; e < 1536; e += 1024)
        Sp_l[e] = part[e] + part[1536 + e] + part[3072 + e] + part[4608 + e];
    __syncthreads();

    // ---- S[ch,c] = sum_i Wk[i,ch] * Sp[i,c] ----
    for (int e = tid; e < 1536; e += 1024) {
        const int c = e & 63, ch = e >> 6;
        float s = 0.f;
        #pragma unroll
        for (int i = 0; i < 24; ++i) s += Wk[i * 24 + ch] * Sp_l[i * 64 + c];
        S_l[e] = s;
    }
    __syncthreads();

    // ---- att[ch,d] = QSCALE*rescale[h] * sum_c S[ch,c]*Wq[c,h*64+d] ----
    for (int e = tid; e < 1536; e += 1024) {
        const int d = e & 63, ch = e >> 6, h = ch / 3;
        const float* wq = Wq + h * 64 + d;
        const float* sr = S_l + ch * 64;
        float s = 0.f;
        #pragma unroll 8
        for (int c = 0; c < 64; ++c) s += sr[c] * wq[c * 512];
        att[e] = s * QSCALE * rescale[h];
    }
    __syncthreads();

    // ---- softmax over d per row: wave w -> row w, and row w+16 for w<8 ----
    #pragma unroll
    for (int pass = 0; pass < 2; ++pass) {
        const int r = w + pass * 16;
        if (r < 24 && (pass == 0 || w < 8)) {
            float a = att[r * 64 + lane];
            float mx = a;
            #pragma unroll
            for (int off = 32; off >= 1; off >>= 1)
                mx = fmaxf(mx, __shfl_xor(mx, off, 64));
            float e = expf(a - mx);
            float sum = e;
            #pragma unroll
            for (int off = 32; off >= 1; off >>= 1)
                sum += __shfl_xor(sum, off, 64);
            att[r * 64 + lane] = e / sum;
        }
    }
    __syncthreads();

    // ---- M[ch,c] = sum_d P[ch,d] * Wv[c,h*64+d]  (into S_l, now dead) ----
    for (int e = tid; e < 1536; e += 1024) {
        const int c = e & 63, ch = e >> 6, h = ch / 3;
        const float* pr = att + ch * 64;
        const float* wv = Wv + c * 512 + h * 64;
        float s = 0.f;
        #pragma unroll
        for (int d = 0; d < 64; ++d) s += pr[d] * wv[d];
        S_l[e] = s;
    }
    __syncthreads();

    // ---- Pt[o,c] = sum_{k,h} M[(h*3+k),c] * Wp[(k*8+h),o]  (plain store) ----
    for (int e = tid; e < 1536; e += 1024) {
        const int c = e & 63, o = e >> 6;
        float s = 0.f;
        #pragma unroll
        for (int k = 0; k < 3; ++k)
            #pragma unroll
            for (int h = 0; h < 8; ++h)
                s += S_l[(h * 3 + k) * 64 + c] * Wp[(k * 8 + h) * 24 + o];
        Pt[b * 1536 + e] = s;
    }
}

// ---------------------------------------------------------------------------
// K3 (R9 v4, verbatim, proven 44us): conv with LDS-staged ph3 projection.
// ---------------------------------------------------------------------------
__global__ __launch_bounds__(192, 2) void conv_fused(
    const float* __restrict__ imap, const float* __restrict__ Wk,
    const float* __restrict__ c1w,  const float* __restrict__ fea,
    const float* __restrict__ c2w,  const float* __restrict__ Pt,
    const float* __restrict__ bp,   float* __restrict__ outp)
{
    __shared__ __align__(16) float smem[8784];
    float* kbuf = smem;               // ph1/ph2: 144*28 = 4032
    float* feat = smem;               // ph3: 64 pix * 68 = 4352 (reuses kbuf)
    float* y1l  = smem + 4352;        // 100*28 = 2800
    float* ptl  = smem + 7152;        // 24*68 = 1632

    const int tid = threadIdx.x;
    const int blk = blockIdx.x;
    const int b = blk >> 8, ti = (blk >> 4) & 15, tj = blk & 15;
    const int i0 = ti * 8, j0 = tj * 8;
    const int o = tid % 24, jj = tid / 24;   // o: out-channel; jj: 0..7
    const int g = o >> 3;

    // ---- phase 1: kproj on the 12x12 halo (threads 0..143) ----
    if (tid < 144) {
        const int pi = tid / 12, pj = tid % 12;
        const int gi = i0 + pi - 2, gj = j0 + pj - 2;
        float kv[24];
        #pragma unroll
        for (int j = 0; j < 24; ++j) kv[j] = 0.f;
        if (gi >= 0 && gi < HH && gj >= 0 && gj < WW) {
            const float4* m4 = (const float4*)(imap + (((long)b * HH + gi) * WW + gj) * 24);
            float m[24];
            #pragma unroll
            for (int i = 0; i < 6; ++i) {
                float4 v = m4[i];
                m[4*i+0]=v.x; m[4*i+1]=v.y; m[4*i+2]=v.z; m[4*i+3]=v.w;
            }
            for (int i = 0; i < 24; ++i) {
                float mi = m[i];
                #pragma unroll
                for (int j = 0; j < 24; ++j) kv[j] += mi * Wk[i * 24 + j];
            }
        }
        #pragma unroll
        for (int j = 0; j < 24; ++j) kbuf[tid * 28 + j] = kv[j];
    }
    __syncthreads();

    // ---- phase 2: y1 = gelu(conv1) on 10x10 -> y1l ----
    {
        float wr[8][9];   // wr[ic][di*3+dj], OIHW-linear
        {
            const float4* wp = (const float4*)(c1w + o * 72);
            #pragma unroll
            for (int t = 0; t < 18; ++t) ((float4*)wr)[t] = wp[t];
        }
        for (int task = tid; task < 240; task += 192) {
            const int r = task / 24;           // y1l row 0..9
            float wc[3][3][8];                 // [col slot][di][ic]
            #pragma unroll
            for (int slot = 0; slot < 2; ++slot)
                #pragma unroll
                for (int di = 0; di < 3; ++di) {
                    const float* p = kbuf + ((r + di) * 12 + slot) * 28 + g * 8;
                    *(float4*)&wc[slot][di][0] = *(const float4*)(p);
                    *(float4*)&wc[slot][di][4] = *(const float4*)(p + 4);
                }
            #pragma unroll
            for (int c = 0; c < 10; ++c) {
                const int s2 = (c + 2) % 3;
                #pragma unroll
                for (int di = 0; di < 3; ++di) {
                    const float* p = kbuf + ((r + di) * 12 + (c + 2)) * 28 + g * 8;
                    *(float4*)&wc[s2][di][0] = *(const float4*)(p);
                    *(float4*)&wc[s2][di][4] = *(const float4*)(p + 4);
                }
                float s = 0.f;
                #pragma unroll
                for (int dj = 0; dj < 3; ++dj) {
                    const int sl = (c + dj) % 3;
                    #pragma unroll
                    for (int di = 0; di < 3; ++di)
                        #pragma unroll
                        for (int ic = 0; ic < 8; ++ic)
                            s += wc[sl][di][ic] * wr[ic][di * 3 + dj];
                }
                const int gi = i0 + r - 1, gj = j0 + c - 1;
                float val = 0.f;
                if (gi >= 0 && gi < HH && gj >= 0 && gj < WW)
                    val = 0.5f * s * (1.f + erff(s * 0.70710678f));
                y1l[(r * 10 + c) * 28 + o] = val;
            }
        }
    }
    __syncthreads();   // kbuf dead; feat may now overwrite it

    // ---- phase 3a: stage fea tile + Pt row into LDS (coalesced) ----
    {
        const float4* feaT4 = (const float4*)(fea + (((long)(b * HH + i0)) * WW + j0) * 64);
        float4* feat4 = (float4*)feat;
        for (int e = tid; e < 1024; e += 192) {
            const int pix = e >> 4, cq = e & 15;      // pix = ii*8+jj
            feat4[pix * 17 + cq] =
                feaT4[((long)(pix >> 3) * WW + (pix & 7)) * 16 + cq];
        }
        const float4* Pt4 = (const float4*)(Pt + b * 1536);
        float4* ptl4 = (float4*)ptl;
        for (int e = tid; e < 384; e += 192) {
            const int o2 = e >> 4, cq = e & 15;
            ptl4[o2 * 17 + cq] = Pt4[o2 * 16 + cq];
        }
    }
    __syncthreads();

    // ---- phase 3b: proj from LDS + conv2(y1l) ----
    float wr[8][9];
    {
        const float4* wp = (const float4*)(c2w + o * 72);
        #pragma unroll
        for (int t = 0; t < 18; ++t) ((float4*)wr)[t] = wp[t];
    }

    float acc[8];
    {
        const float bo = bp[o];
        #pragma unroll
        for (int ii = 0; ii < 8; ++ii) acc[ii] = bo;
        const float4* pr4 = (const float4*)(ptl + o * 68);
        for (int cq = 0; cq < 16; ++cq) {
            float4 p = pr4[cq];
            #pragma unroll
            for (int ii = 0; ii < 8; ++ii) {
                float4 f = ((const float4*)(feat + (ii * 8 + jj) * 68))[cq];
                acc[ii] += f.x * p.x + f.y * p.y + f.z * p.z + f.w * p.w;
            }
        }
    }

    float win[3][3][8];   // [row slot][dj][ic]
    #define LROW(R, SLOT)                                                     \
    {                                                                         \
        const float* rp_ = y1l + ((R) * 10 + jj) * 28 + g * 8;                \
        *(float4*)&win[SLOT][0][0] = *(const float4*)(rp_);                   \
        *(float4*)&win[SLOT][0][4] = *(const float4*)(rp_ + 4);               \
        *(float4*)&win[SLOT][1][0] = *(const float4*)(rp_ + 28);              \
        *(float4*)&win[SLOT][1][4] = *(const float4*)(rp_ + 32);              \
        *(float4*)&win[SLOT][2][0] = *(const float4*)(rp_ + 56);              \
        *(float4*)&win[SLOT][2][4] = *(const float4*)(rp_ + 60);              \
    }

    LROW(0, 0)
    LROW(1, 1)
    #pragma unroll
    for (int ii = 0; ii < 8; ++ii) {
        LROW(ii + 2, (ii + 2) % 3)
        float s = 0.f;
        #pragma unroll
        for (int di = 0; di < 3; ++di) {
            const int slot = (ii + di) % 3;
            #pragma unroll
            for (int dj = 0; dj < 3; ++dj)
                #pragma unroll
                for (int ic = 0; ic < 8; ++ic)
                    s += win[slot][dj][ic] * wr[ic][di * 3 + dj];
        }
        outp[((long)((b * HH + i0 + ii) * WW + j0)) * 24 + tid] = acc[ii] + s;
    }
    #undef LROW
}

// ---------------------------------------------------------------------------
extern "C" void kernel_launch(void* const* d_in, const int* in_sizes, int n_in,
                              void* d_out, int out_size, void* d_ws, size_t ws_size,
                              hipStream_t stream) {
    const float* x_in    = (const float*)d_in[0];
    const float* fea     = (const float*)d_in[1];
    const float* imap    = (const float*)d_in[2];
    const float* Wq      = (const float*)d_in[3];
    const float* Wk      = (const float*)d_in[4];
    const float* Wv      = (const float*)d_in[5];
    const float* rescale = (const float*)d_in[6];
    const float* Wp      = (const float*)d_in[7];
    const float* bp      = (const float*)d_in[8];
    const float* c1w     = (const float*)d_in[9];
    const float* c2w     = (const float*)d_in[10];
    float* out = (float*)d_out;

    float* ws      = (float*)d_ws;
    float* Sp_part = ws;                     // 1024*1536 = 1,572,864 floats
    float* Pt      = ws + 1572864;           // 6,144 floats

    s_reduce<<<1024, 256, 0, stream>>>(imap, x_in, Sp_part);
    attn_fused<<<4, 1024, 0, stream>>>(Sp_part, Wk, Wq, Wv, rescale, Wp, Pt);
    conv_fused<<<BB * 256, 192, 0, stream>>>(imap, Wk, c1w, fea, c2w, Pt, bp, out);
}

// Round 11
// 176.886 us; speedup vs baseline: 1.0118x; 1.0118x over previous
//
#include <hip/hip_runtime.h>
#include <math.h>

#define HEADS 8
#define DIM   64
#define DK    24
#define DHK   3
#define BB    4
#define HH    128
#define WW    128
#define NN    (HH*WW)
#define QSCALE 0.125f

// ---------------------------------------------------------------------------
// K1 v5 (R10, verbatim): token-partial reduce. grid 1024 x 256 thr,
// 4-wave LDS merge (24.6KB -> ~6 blocks/CU), plain stores.
// ---------------------------------------------------------------------------
__global__ __launch_bounds__(256) void s_reduce(
    const float* __restrict__ imap,   // [B*N,24]
    const float* __restrict__ x,      // [B*N,64]
    float* __restrict__ Sp_part)      // [1024,1536]
{
    __shared__ float part[4 * 1540];    // 24.6 KB, stride 1540 (pad: %32==4)
    const int tid = threadIdx.x;
    const int blk = blockIdx.x;
    const int b = blk >> 8, chunk = blk & 255;
    const int w = tid >> 6, lane = tid & 63;
    const int cq = lane & 15;         // c = cq*4
    const int ig = lane >> 4;         // i = ig*6 .. +5

    const long tok0 = (long)b * NN + chunk * 64 + w * 16;
    const float* xp = x    + tok0 * 64 + cq * 4;
    const float* mp = imap + tok0 * 24 + ig * 6;

    float acc[6][4];
    #pragma unroll
    for (int r = 0; r < 6; ++r)
        #pragma unroll
        for (int q = 0; q < 4; ++q) acc[r][q] = 0.f;

    #pragma unroll 4
    for (int t = 0; t < 16; ++t) {
        float4 xv = *(const float4*)(xp + t * 64);
        float2 m0 = *(const float2*)(mp + t * 24);
        float2 m1 = *(const float2*)(mp + t * 24 + 2);
        float2 m2 = *(const float2*)(mp + t * 24 + 4);
        float mm[6] = {m0.x, m0.y, m1.x, m1.y, m2.x, m2.y};
        #pragma unroll
        for (int r = 0; r < 6; ++r) {
            acc[r][0] += mm[r] * xv.x;
            acc[r][1] += mm[r] * xv.y;
            acc[r][2] += mm[r] * xv.z;
            acc[r][3] += mm[r] * xv.w;
        }
    }

    float* pp = part + w * 1540;
    #pragma unroll
    for (int r = 0; r < 6; ++r) {
        float4 v = {acc[r][0], acc[r][1], acc[r][2], acc[r][3]};
        *(float4*)(pp + (ig * 6 + r) * 64 + cq * 4) = v;
    }
    __syncthreads();

    for (int e = tid; e < 1536; e += 256) {
        Sp_part[(long)blk * 1536 + e] =
            part[e] + part[1540 + e] + part[3080 + e] + part[4620 + e];
    }
}

// ---------------------------------------------------------------------------
// K2 v5 (R10, verbatim): one block per batch, single-pass slab reduce +
// full attention, plain Pt stores (no atomics, no pre-zero).
// ---------------------------------------------------------------------------
__global__ __launch_bounds__(1024) void attn_fused(
    const float* __restrict__ Sp_part, // [1024,1536]
    const float* __restrict__ Wk,      // [24,24]
    const float* __restrict__ Wq,      // [64,512]
    const float* __restrict__ Wv,      // [64,512]
    const float* __restrict__ rescale, // [8]
    const float* __restrict__ Wp,      // [24,24]
    float* __restrict__ Pt)            // [4,1536] plain-stored here
{
    __shared__ float part[4 * 1536];   // 24.6 KB
    __shared__ float Sp_l[1536];
    __shared__ float S_l[1536];        // S rows; later reused for M
    __shared__ float att[1536];

    const int tid = threadIdx.x, b = blockIdx.x;
    const int w = tid >> 6, lane = tid & 63;

    // ---- 2-level slab reduce: 256 slabs of batch b ----
    {
        const int p = tid & 255, q = tid >> 8;
        const float* base = Sp_part + ((long)(b * 256 + q * 64)) * 1536;
        #pragma unroll
        for (int k = 0; k < 6; ++k) {
            const int e = k * 256 + p;
            const float* pp = base + e;
            float s = 0.f;
            #pragma unroll 16
            for (int sb = 0; sb < 64; ++sb) s += pp[(long)sb * 1536];
            part[q * 1536 + e] = s;
        }
    }
    __syncthreads();
    for (int e = tid; e < 1536; e += 1024)
        Sp_l[e] = part[e] + part[1536 + e] + part[3072 + e] + part[4608 + e];
    __syncthreads();

    // ---- S[ch,c] = sum_i Wk[i,ch] * Sp[i,c] ----
    for (int e = tid; e < 1536; e += 1024) {
        const int c = e & 63, ch = e >> 6;
        float s = 0.f;
        #pragma unroll
        for (int i = 0; i < 24; ++i) s += Wk[i * 24 + ch] * Sp_l[i * 64 + c];
        S_l[e] = s;
    }
    __syncthreads();

    // ---- att[ch,d] = QSCALE*rescale[h] * sum_c S[ch,c]*Wq[c,h*64+d] ----
    for (int e = tid; e < 1536; e += 1024) {
        const int d = e & 63, ch = e >> 6, h = ch / 3;
        const float* wq = Wq + h * 64 + d;
        const float* sr = S_l + ch * 64;
        float s = 0.f;
        #pragma unroll 8
        for (int c = 0; c < 64; ++c) s += sr[c] * wq[c * 512];
        att[e] = s * QSCALE * rescale[h];
    }
    __syncthreads();

    // ---- softmax over d per row: wave w -> row w, and row w+16 for w<8 ----
    #pragma unroll
    for (int pass = 0; pass < 2; ++pass) {
        const int r = w + pass * 16;
        if (r < 24 && (pass == 0 || w < 8)) {
            float a = att[r * 64 + lane];
            float mx = a;
            #pragma unroll
            for (int off = 32; off >= 1; off >>= 1)
                mx = fmaxf(mx, __shfl_xor(mx, off, 64));
            float e = expf(a - mx);
            float sum = e;
            #pragma unroll
            for (int off = 32; off >= 1; off >>= 1)
                sum += __shfl_xor(sum, off, 64);
            att[r * 64 + lane] = e / sum;
        }
    }
    __syncthreads();

    // ---- M[ch,c] = sum_d P[ch,d] * Wv[c,h*64+d]  (into S_l, now dead) ----
    for (int e = tid; e < 1536; e += 1024) {
        const int c = e & 63, ch = e >> 6, h = ch / 3;
        const float* pr = att + ch * 64;
        const float* wv = Wv + c * 512 + h * 64;
        float s = 0.f;
        #pragma unroll
        for (int d = 0; d < 64; ++d) s += pr[d] * wv[d];
        S_l[e] = s;
    }
    __syncthreads();

    // ---- Pt[o,c] = sum_{k,h} M[(h*3+k),c] * Wp[(k*8+h),o]  (plain store) ----
    for (int e = tid; e < 1536; e += 1024) {
        const int c = e & 63, o = e >> 6;
        float s = 0.f;
        #pragma unroll
        for (int k = 0; k < 3; ++k)
            #pragma unroll
            for (int h = 0; h < 8; ++h)
                s += S_l[(h * 3 + k) * 64 + c] * Wp[(k * 8 + h) * 24 + o];
        Pt[b * 1536 + e] = s;
    }
}

// ---------------------------------------------------------------------------
// K3 v5: R9 body with ONE change -- drop the ptl (Pt row) LDS stage.
// Pt is a 6KB per-batch row shared by 256 blocks => guaranteed L2/LLC
// resident; 16 independent float4 loads/thread (exact R4 pattern).
// LDS 35.3KB -> 28.6KB => 5 blocks/CU (was 4) = 15 waves/CU, +25% latency
// hiding on a kernel that is pure latency-bound (VALU 29%, HBM 5%).
// feat staging (R9's proven +4us win) kept.
// smem: [0..4352) feat (ph1/2 alias kbuf [0..4032)), [4352..7152) y1l.
// ---------------------------------------------------------------------------
__global__ __launch_bounds__(192, 2) void conv_fused(
    const float* __restrict__ imap, const float* __restrict__ Wk,
    const float* __restrict__ c1w,  const float* __restrict__ fea,
    const float* __restrict__ c2w,  const float* __restrict__ Pt,
    const float* __restrict__ bp,   float* __restrict__ outp)
{
    __shared__ __align__(16) float smem[7152];
    float* kbuf = smem;               // ph1/ph2: 144*28 = 4032
    float* feat = smem;               // ph3: 64 pix * 68 = 4352 (reuses kbuf)
    float* y1l  = smem + 4352;        // 100*28 = 2800

    const int tid = threadIdx.x;
    const int blk = blockIdx.x;
    const int b = blk >> 8, ti = (blk >> 4) & 15, tj = blk & 15;
    const int i0 = ti * 8, j0 = tj * 8;
    const int o = tid % 24, jj = tid / 24;   // o: out-channel; jj: 0..7
    const int g = o >> 3;

    // ---- phase 1: kproj on the 12x12 halo (threads 0..143) ----
    if (tid < 144) {
        const int pi = tid / 12, pj = tid % 12;
        const int gi = i0 + pi - 2, gj = j0 + pj - 2;
        float kv[24];
        #pragma unroll
        for (int j = 0; j < 24; ++j) kv[j] = 0.f;
        if (gi >= 0 && gi < HH && gj >= 0 && gj < WW) {
            const float4* m4 = (const float4*)(imap + (((long)b * HH + gi) * WW + gj) * 24);
            float m[24];
            #pragma unroll
            for (int i = 0; i < 6; ++i) {
                float4 v = m4[i];
                m[4*i+0]=v.x; m[4*i+1]=v.y; m[4*i+2]=v.z; m[4*i+3]=v.w;
            }
            for (int i = 0; i < 24; ++i) {
                float mi = m[i];
                #pragma unroll
                for (int j = 0; j < 24; ++j) kv[j] += mi * Wk[i * 24 + j];
            }
        }
        #pragma unroll
        for (int j = 0; j < 24; ++j) kbuf[tid * 28 + j] = kv[j];
    }
    __syncthreads();

    // ---- phase 2: y1 = gelu(conv1) on 10x10 -> y1l ----
    {
        float wr[8][9];   // wr[ic][di*3+dj], OIHW-linear
        {
            const float4* wp = (const float4*)(c1w + o * 72);
            #pragma unroll
            for (int t = 0; t < 18; ++t) ((float4*)wr)[t] = wp[t];
        }
        for (int task = tid; task < 240; task += 192) {
            const int r = task / 24;           // y1l row 0..9
            float wc[3][3][8];                 // [col slot][di][ic]
            #pragma unroll
            for (int slot = 0; slot < 2; ++slot)
                #pragma unroll
                for (int di = 0; di < 3; ++di) {
                    const float* p = kbuf + ((r + di) * 12 + slot) * 28 + g * 8;
                    *(float4*)&wc[slot][di][0] = *(const float4*)(p);
                    *(float4*)&wc[slot][di][4] = *(const float4*)(p + 4);
                }
            #pragma unroll
            for (int c = 0; c < 10; ++c) {
                const int s2 = (c + 2) % 3;
                #pragma unroll
                for (int di = 0; di < 3; ++di) {
                    const float* p = kbuf + ((r + di) * 12 + (c + 2)) * 28 + g * 8;
                    *(float4*)&wc[s2][di][0] = *(const float4*)(p);
                    *(float4*)&wc[s2][di][4] = *(const float4*)(p + 4);
                }
                float s = 0.f;
                #pragma unroll
                for (int dj = 0; dj < 3; ++dj) {
                    const int sl = (c + dj) % 3;
                    #pragma unroll
                    for (int di = 0; di < 3; ++di)
                        #pragma unroll
                        for (int ic = 0; ic < 8; ++ic)
                            s += wc[sl][di][ic] * wr[ic][di * 3 + dj];
                }
                const int gi = i0 + r - 1, gj = j0 + c - 1;
                float val = 0.f;
                if (gi >= 0 && gi < HH && gj >= 0 && gj < WW)
                    val = 0.5f * s * (1.f + erff(s * 0.70710678f));
                y1l[(r * 10 + c) * 28 + o] = val;
            }
        }
    }
    __syncthreads();   // kbuf dead; feat may now overwrite it

    // ---- phase 3a: stage fea tile into LDS (coalesced, stride 68) ----
    {
        const float4* feaT4 = (const float4*)(fea + (((long)(b * HH + i0)) * WW + j0) * 64);
        float4* feat4 = (float4*)feat;
        for (int e = tid; e < 1024; e += 192) {
            const int pix = e >> 4, cq = e & 15;      // pix = ii*8+jj
            feat4[pix * 17 + cq] =
                feaT4[((long)(pix >> 3) * WW + (pix & 7)) * 16 + cq];
        }
    }
    __syncthreads();

    // ---- phase 3b: proj (Pt from L2, fea from LDS) + conv2(y1l) ----
    float wr[8][9];
    {
        const float4* wp = (const float4*)(c2w + o * 72);
        #pragma unroll
        for (int t = 0; t < 18; ++t) ((float4*)wr)[t] = wp[t];
    }

    float acc[8];
    {
        const float bo = bp[o];
        #pragma unroll
        for (int ii = 0; ii < 8; ++ii) acc[ii] = bo;
        const float4* pr4 = (const float4*)(Pt + b * 1536 + o * 64);
        for (int cq = 0; cq < 16; ++cq) {
            float4 p = pr4[cq];
            #pragma unroll
            for (int ii = 0; ii < 8; ++ii) {
                float4 f = ((const float4*)(feat + (ii * 8 + jj) * 68))[cq];
                acc[ii] += f.x * p.x + f.y * p.y + f.z * p.z + f.w * p.w;
            }
        }
    }

    float win[3][3][8];   // [row slot][dj][ic]
    #define LROW(R, SLOT)                                                     \
    {                                                                         \
        const float* rp_ = y1l + ((R) * 10 + jj) * 28 + g * 8;                \
        *(float4*)&win[SLOT][0][0] = *(const float4*)(rp_);                   \
        *(float4*)&win[SLOT][0][4] = *(const float4*)(rp_ + 4);               \
        *(float4*)&win[SLOT][1][0] = *(const float4*)(rp_ + 28);              \
        *(float4*)&win[SLOT][1][4] = *(const float4*)(rp_ + 32);              \
        *(float4*)&win[SLOT][2][0] = *(const float4*)(rp_ + 56);              \
        *(float4*)&win[SLOT][2][4] = *(const float4*)(rp_ + 60);              \
    }

    LROW(0, 0)
    LROW(1, 1)
    #pragma unroll
    for (int ii = 0; ii < 8; ++ii) {
        LROW(ii + 2, (ii + 2) % 3)
        float s = 0.f;
        #pragma unroll
        for (int di = 0; di < 3; ++di) {
            const int slot = (ii + di) % 3;
            #pragma unroll
            for (int dj = 0; dj < 3; ++dj)
                #pragma unroll
                for (int ic = 0; ic < 8; ++ic)
                    s += win[slot][dj][ic] * wr[ic][di * 3 + dj];
        }
        outp[((long)((b * HH + i0 + ii) * WW + j0)) * 24 + tid] = acc[ii] + s;
    }
    #undef LROW
}

// ---------------------------------------------------------------------------
extern "C" void kernel_launch(void* const* d_in, const int* in_sizes, int n_in,
                              void* d_out, int out_size, void* d_ws, size_t ws_size,
                              hipStream_t stream) {
    const float* x_in    = (const float*)d_in[0];
    const float* fea     = (const float*)d_in[1];
    const float* imap    = (const float*)d_in[2];
    const float* Wq      = (const float*)d_in[3];
    const float* Wk      = (const float*)d_in[4];
    const float* Wv      = (const float*)d_in[5];
    const float* rescale = (const float*)d_in[6];
    const float* Wp      = (const float*)d_in[7];
    const float* bp      = (const float*)d_in[8];
    const float* c1w     = (const float*)d_in[9];
    const float* c2w     = (const float*)d_in[10];
    float* out = (float*)d_out;

    float* ws      = (float*)d_ws;
    float* Sp_part = ws;                     // 1024*1536 = 1,572,864 floats
    float* Pt      = ws + 1572864;           // 6,144 floats

    s_reduce<<<1024, 256, 0, stream>>>(imap, x_in, Sp_part);
    attn_fused<<<4, 1024, 0, stream>>>(Sp_part, Wk, Wq, Wv, rescale, Wp, Pt);
    conv_fused<<<BB * 256, 192, 0, stream>>>(imap, Wk, c1w, fea, c2w, Pt, bp, out);
}

// Round 12
// 164.311 us; speedup vs baseline: 1.0893x; 1.0765x over previous
//
#include <hip/hip_runtime.h>
#include <math.h>

#define HEADS 8
#define DIM   64
#define DK    24
#define DHK   3
#define BB    4
#define HH    128
#define WW    128
#define NN    (HH*WW)
#define QSCALE 0.125f

// ---------------------------------------------------------------------------
// K1 v5 (R10, verbatim): token-partial reduce. grid 1024 x 256 thr,
// 4-wave LDS merge (24.6KB), plain stores -> Sp_part[1024][1536].
// ---------------------------------------------------------------------------
__global__ __launch_bounds__(256) void s_reduce(
    const float* __restrict__ imap,   // [B*N,24]
    const float* __restrict__ x,      // [B*N,64]
    float* __restrict__ Sp_part)      // [1024,1536]
{
    __shared__ float part[4 * 1540];    // 24.6 KB, stride 1540 (pad: %32==4)
    const int tid = threadIdx.x;
    const int blk = blockIdx.x;
    const int b = blk >> 8, chunk = blk & 255;
    const int w = tid >> 6, lane = tid & 63;
    const int cq = lane & 15;         // c = cq*4
    const int ig = lane >> 4;         // i = ig*6 .. +5

    const long tok0 = (long)b * NN + chunk * 64 + w * 16;
    const float* xp = x    + tok0 * 64 + cq * 4;
    const float* mp = imap + tok0 * 24 + ig * 6;

    float acc[6][4];
    #pragma unroll
    for (int r = 0; r < 6; ++r)
        #pragma unroll
        for (int q = 0; q < 4; ++q) acc[r][q] = 0.f;

    #pragma unroll 4
    for (int t = 0; t < 16; ++t) {
        float4 xv = *(const float4*)(xp + t * 64);
        float2 m0 = *(const float2*)(mp + t * 24);
        float2 m1 = *(const float2*)(mp + t * 24 + 2);
        float2 m2 = *(const float2*)(mp + t * 24 + 4);
        float mm[6] = {m0.x, m0.y, m1.x, m1.y, m2.x, m2.y};
        #pragma unroll
        for (int r = 0; r < 6; ++r) {
            acc[r][0] += mm[r] * xv.x;
            acc[r][1] += mm[r] * xv.y;
            acc[r][2] += mm[r] * xv.z;
            acc[r][3] += mm[r] * xv.w;
        }
    }

    float* pp = part + w * 1540;
    #pragma unroll
    for (int r = 0; r < 6; ++r) {
        float4 v = {acc[r][0], acc[r][1], acc[r][2], acc[r][3]};
        *(float4*)(pp + (ig * 6 + r) * 64 + cq * 4) = v;
    }
    __syncthreads();

    for (int e = tid; e < 1536; e += 256) {
        Sp_part[(long)blk * 1536 + e] =
            part[e] + part[1540 + e] + part[3080 + e] + part[4620 + e];
    }
}

// ---------------------------------------------------------------------------
// K2a (NEW): parallel slab reduce 1024 -> 4. R11 counters showed the old
// in-attention reduce ran on 4 CUs at 84 GB/s, 0.6% occupancy, 44us.
// grid 96 (4 b x 24 egroups of 64 elems) x 256 thr: wave w sums slab-quarter
// w (64 slabs) for 64 contiguous elements (coalesced 256B segments,
// unroll-16 MLP), LDS merge, plain store Sp[4][1536]. 6.3MB over 96 CUs.
// ---------------------------------------------------------------------------
__global__ __launch_bounds__(256) void slab_reduce(
    const float* __restrict__ Sp_part, // [1024,1536]
    float* __restrict__ Sp)            // [4,1536]
{
    __shared__ float red[256];
    const int tid = threadIdx.x;
    const int blk = blockIdx.x;
    const int b = blk / 24, eg = blk % 24;
    const int w = tid >> 6, lane = tid & 63;
    const int e = eg * 64 + lane;

    const float* p = Sp_part + ((long)(b * 256 + w * 64)) * 1536 + e;
    float s = 0.f;
    #pragma unroll 16
    for (int sb = 0; sb < 64; ++sb) s += p[(long)sb * 1536];
    red[w * 64 + lane] = s;
    __syncthreads();

    if (tid < 64)
        Sp[b * 1536 + eg * 64 + tid] =
            red[tid] + red[64 + tid] + red[128 + tid] + red[192 + tid];
}

// ---------------------------------------------------------------------------
// K2b: attention only (R10 body with the slab reduce replaced by a 6KB
// Sp[b] load). grid 4 x 1024. Plain Pt stores, no atomics, no pre-zero.
// ---------------------------------------------------------------------------
__global__ __launch_bounds__(1024) void attn_fused(
    const float* __restrict__ Sp,      // [4,1536]
    const float* __restrict__ Wk,      // [24,24]
    const float* __restrict__ Wq,      // [64,512]
    const float* __restrict__ Wv,      // [64,512]
    const float* __restrict__ rescale, // [8]
    const float* __restrict__ Wp,      // [24,24]
    float* __restrict__ Pt)            // [4,1536] plain-stored here
{
    __shared__ float Sp_l[1536];
    __shared__ float S_l[1536];        // S rows; later reused for M
    __shared__ float att[1536];

    const int tid = threadIdx.x, b = blockIdx.x;
    const int w = tid >> 6, lane = tid & 63;

    for (int e = tid; e < 1536; e += 1024) Sp_l[e] = Sp[b * 1536 + e];
    __syncthreads();

    // ---- S[ch,c] = sum_i Wk[i,ch] * Sp[i,c] ----
    for (int e = tid; e < 1536; e += 1024) {
        const int c = e & 63, ch = e >> 6;
        float s = 0.f;
        #pragma unroll
        for (int i = 0; i < 24; ++i) s += Wk[i * 24 + ch] * Sp_l[i * 64 + c];
        S_l[e] = s;
    }
    __syncthreads();

    // ---- att[ch,d] = QSCALE*rescale[h] * sum_c S[ch,c]*Wq[c,h*64+d] ----
    for (int e = tid; e < 1536; e += 1024) {
        const int d = e & 63, ch = e >> 6, h = ch / 3;
        const float* wq = Wq + h * 64 + d;
        const float* sr = S_l + ch * 64;
        float s = 0.f;
        #pragma unroll 8
        for (int c = 0; c < 64; ++c) s += sr[c] * wq[c * 512];
        att[e] = s * QSCALE * rescale[h];
    }
    __syncthreads();

    // ---- softmax over d per row: wave w -> row w, and row w+16 for w<8 ----
    #pragma unroll
    for (int pass = 0; pass < 2; ++pass) {
        const int r = w + pass * 16;
        if (r < 24 && (pass == 0 || w < 8)) {
            float a = att[r * 64 + lane];
            float mx = a;
            #pragma unroll
            for (int off = 32; off >= 1; off >>= 1)
                mx = fmaxf(mx, __shfl_xor(mx, off, 64));
            float e = expf(a - mx);
            float sum = e;
            #pragma unroll
            for (int off = 32; off >= 1; off >>= 1)
                sum += __shfl_xor(sum, off, 64);
            att[r * 64 + lane] = e / sum;
        }
    }
    __syncthreads();

    // ---- M[ch,c] = sum_d P[ch,d] * Wv[c,h*64+d]  (into S_l, now dead) ----
    for (int e = tid; e < 1536; e += 1024) {
        const int c = e & 63, ch = e >> 6, h = ch / 3;
        const float* pr = att + ch * 64;
        const float* wv = Wv + c * 512 + h * 64;
        float s = 0.f;
        #pragma unroll
        for (int d = 0; d < 64; ++d) s += pr[d] * wv[d];
        S_l[e] = s;
    }
    __syncthreads();

    // ---- Pt[o,c] = sum_{k,h} M[(h*3+k),c] * Wp[(k*8+h),o]  (plain store) ----
    for (int e = tid; e < 1536; e += 1024) {
        const int c = e & 63, o = e >> 6;
        float s = 0.f;
        #pragma unroll
        for (int k = 0; k < 3; ++k)
            #pragma unroll
            for (int h = 0; h < 8; ++h)
                s += S_l[(h * 3 + k) * 64 + c] * Wp[(k * 8 + h) * 24 + o];
        Pt[b * 1536 + e] = s;
    }
}

// ---------------------------------------------------------------------------
// K3 (R11, verbatim): conv with LDS-staged fea, Pt from L2.
// ---------------------------------------------------------------------------
__global__ __launch_bounds__(192, 2) void conv_fused(
    const float* __restrict__ imap, const float* __restrict__ Wk,
    const float* __restrict__ c1w,  const float* __restrict__ fea,
    const float* __restrict__ c2w,  const float* __restrict__ Pt,
    const float* __restrict__ bp,   float* __restrict__ outp)
{
    __shared__ __align__(16) float smem[7152];
    float* kbuf = smem;               // ph1/ph2: 144*28 = 4032
    float* feat = smem;               // ph3: 64 pix * 68 = 4352 (reuses kbuf)
    float* y1l  = smem + 4352;        // 100*28 = 2800

    const int tid = threadIdx.x;
    const int blk = blockIdx.x;
    const int b = blk >> 8, ti = (blk >> 4) & 15, tj = blk & 15;
    const int i0 = ti * 8, j0 = tj * 8;
    const int o = tid % 24, jj = tid / 24;   // o: out-channel; jj: 0..7
    const int g = o >> 3;

    // ---- phase 1: kproj on the 12x12 halo (threads 0..143) ----
    if (tid < 144) {
        const int pi = tid / 12, pj = tid % 12;
        const int gi = i0 + pi - 2, gj = j0 + pj - 2;
        float kv[24];
        #pragma unroll
        for (int j = 0; j < 24; ++j) kv[j] = 0.f;
        if (gi >= 0 && gi < HH && gj >= 0 && gj < WW) {
            const float4* m4 = (const float4*)(imap + (((long)b * HH + gi) * WW + gj) * 24);
            float m[24];
            #pragma unroll
            for (int i = 0; i < 6; ++i) {
                float4 v = m4[i];
                m[4*i+0]=v.x; m[4*i+1]=v.y; m[4*i+2]=v.z; m[4*i+3]=v.w;
            }
            for (int i = 0; i < 24; ++i) {
                float mi = m[i];
                #pragma unroll
                for (int j = 0; j < 24; ++j) kv[j] += mi * Wk[i * 24 + j];
            }
        }
        #pragma unroll
        for (int j = 0; j < 24; ++j) kbuf[tid * 28 + j] = kv[j];
    }
    __syncthreads();

    // ---- phase 2: y1 = gelu(conv1) on 10x10 -> y1l ----
    {
        float wr[8][9];   // wr[ic][di*3+dj], OIHW-linear
        {
            const float4* wp = (const float4*)(c1w + o * 72);
            #pragma unroll
            for (int t = 0; t < 18; ++t) ((float4*)wr)[t] = wp[t];
        }
        for (int task = tid; task < 240; task += 192) {
            const int r = task / 24;           // y1l row 0..9
            float wc[3][3][8];                 // [col slot][di][ic]
            #pragma unroll
            for (int slot = 0; slot < 2; ++slot)
                #pragma unroll
                for (int di = 0; di < 3; ++di) {
                    const float* p = kbuf + ((r + di) * 12 + slot) * 28 + g * 8;
                    *(float4*)&wc[slot][di][0] = *(const float4*)(p);
                    *(float4*)&wc[slot][di][4] = *(const float4*)(p + 4);
                }
            #pragma unroll
            for (int c = 0; c < 10; ++c) {
                const int s2 = (c + 2) % 3;
                #pragma unroll
                for (int di = 0; di < 3; ++di) {
                    const float* p = kbuf + ((r + di) * 12 + (c + 2)) * 28 + g * 8;
                    *(float4*)&wc[s2][di][0] = *(const float4*)(p);
                    *(float4*)&wc[s2][di][4] = *(const float4*)(p + 4);
                }
                float s = 0.f;
                #pragma unroll
                for (int dj = 0; dj < 3; ++dj) {
                    const int sl = (c + dj) % 3;
                    #pragma unroll
                    for (int di = 0; di < 3; ++di)
                        #pragma unroll
                        for (int ic = 0; ic < 8; ++ic)
                            s += wc[sl][di][ic] * wr[ic][di * 3 + dj];
                }
                const int gi = i0 + r - 1, gj = j0 + c - 1;
                float val = 0.f;
                if (gi >= 0 && gi < HH && gj >= 0 && gj < WW)
                    val = 0.5f * s * (1.f + erff(s * 0.70710678f));
                y1l[(r * 10 + c) * 28 + o] = val;
            }
        }
    }
    __syncthreads();   // kbuf dead; feat may now overwrite it

    // ---- phase 3a: stage fea tile into LDS (coalesced, stride 68) ----
    {
        const float4* feaT4 = (const float4*)(fea + (((long)(b * HH + i0)) * WW + j0) * 64);
        float4* feat4 = (float4*)feat;
        for (int e = tid; e < 1024; e += 192) {
            const int pix = e >> 4, cq = e & 15;      // pix = ii*8+jj
            feat4[pix * 17 + cq] =
                feaT4[((long)(pix >> 3) * WW + (pix & 7)) * 16 + cq];
        }
    }
    __syncthreads();

    // ---- phase 3b: proj (Pt from L2, fea from LDS) + conv2(y1l) ----
    float wr[8][9];
    {
        const float4* wp = (const float4*)(c2w + o * 72);
        #pragma unroll
        for (int t = 0; t < 18; ++t) ((float4*)wr)[t] = wp[t];
    }

    float acc[8];
    {
        const float bo = bp[o];
        #pragma unroll
        for (int ii = 0; ii < 8; ++ii) acc[ii] = bo;
        const float4* pr4 = (const float4*)(Pt + b * 1536 + o * 64);
        for (int cq = 0; cq < 16; ++cq) {
            float4 p = pr4[cq];
            #pragma unroll
            for (int ii = 0; ii < 8; ++ii) {
                float4 f = ((const float4*)(feat + (ii * 8 + jj) * 68))[cq];
                acc[ii] += f.x * p.x + f.y * p.y + f.z * p.z + f.w * p.w;
            }
        }
    }

    float win[3][3][8];   // [row slot][dj][ic]
    #define LROW(R, SLOT)                                                     \
    {                                                                         \
        const float* rp_ = y1l + ((R) * 10 + jj) * 28 + g * 8;                \
        *(float4*)&win[SLOT][0][0] = *(const float4*)(rp_);                   \
        *(float4*)&win[SLOT][0][4] = *(const float4*)(rp_ + 4);               \
        *(float4*)&win[SLOT][1][0] = *(const float4*)(rp_ + 28);              \
        *(float4*)&win[SLOT][1][4] = *(const float4*)(rp_ + 32);              \
        *(float4*)&win[SLOT][2][0] = *(const float4*)(rp_ + 56);              \
        *(float4*)&win[SLOT][2][4] = *(const float4*)(rp_ + 60);              \
    }

    LROW(0, 0)
    LROW(1, 1)
    #pragma unroll
    for (int ii = 0; ii < 8; ++ii) {
        LROW(ii + 2, (ii + 2) % 3)
        float s = 0.f;
        #pragma unroll
        for (int di = 0; di < 3; ++di) {
            const int slot = (ii + di) % 3;
            #pragma unroll
            for (int dj = 0; dj < 3; ++dj)
                #pragma unroll
                for (int ic = 0; ic < 8; ++ic)
                    s += win[slot][dj][ic] * wr[ic][di * 3 + dj];
        }
        outp[((long)((b * HH + i0 + ii) * WW + j0)) * 24 + tid] = acc[ii] + s;
    }
    #undef LROW
}

// ---------------------------------------------------------------------------
extern "C" void kernel_launch(void* const* d_in, const int* in_sizes, int n_in,
                              void* d_out, int out_size, void* d_ws, size_t ws_size,
                              hipStream_t stream) {
    const float* x_in    = (const float*)d_in[0];
    const float* fea     = (const float*)d_in[1];
    const float* imap    = (const float*)d_in[2];
    const float* Wq      = (const float*)d_in[3];
    const float* Wk      = (const float*)d_in[4];
    const float* Wv      = (const float*)d_in[5];
    const float* rescale = (const float*)d_in[6];
    const float* Wp      = (const float*)d_in[7];
    const float* bp      = (const float*)d_in[8];
    const float* c1w     = (const float*)d_in[9];
    const float* c2w     = (const float*)d_in[10];
    float* out = (float*)d_out;

    float* ws      = (float*)d_ws;
    float* Sp_part = ws;                     // 1024*1536 = 1,572,864 floats
    float* Sp      = ws + 1572864;           // 6,144 floats
    float* Pt      = ws + 1579008;           // 6,144 floats

    s_reduce<<<1024, 256, 0, stream>>>(imap, x_in, Sp_part);
    slab_reduce<<<96, 256, 0, stream>>>(Sp_part, Sp);
    attn_fused<<<4, 1024, 0, stream>>>(Sp, Wk, Wq, Wv, rescale, Wp, Pt);
    conv_fused<<<BB * 256, 192, 0, stream>>>(imap, Wk, c1w, fea, c2w, Pt, bp, out);
}